// Round 1
// baseline (1135.689 us; speedup 1.0000x reference)
//
#include <hip/hip_runtime.h>
#include <hip/hip_bf16.h>

#define N 8192

__device__ __forceinline__ float wave_max(float v) {
#pragma unroll
    for (int o = 32; o > 0; o >>= 1) v = fmaxf(v, __shfl_xor(v, o, 64));
    return v;
}
__device__ __forceinline__ float wave_sum(float v) {
#pragma unroll
    for (int o = 32; o > 0; o >>= 1) v += __shfl_xor(v, o, 64);
    return v;
}

// ---------------------------------------------------------------------------
// Generic C[M x Nc] = A[M x K] @ W[Nc x K]^T + bias, optional PReLU.
// 64x64 tile, 256 threads, 4x4 microtile, Kt=16, stride-68 LDS padding.
// All shapes here are multiples of the tile sizes (8192, 512/256/128/64).
// ---------------------------------------------------------------------------
__global__ __launch_bounds__(256) void gemm_bias_act(
    const float* __restrict__ A, const float* __restrict__ W,
    const float* __restrict__ bias, const float* __restrict__ slope_p,
    float* __restrict__ C, int Nc, int K, int act)
{
    __shared__ float As[16][68];
    __shared__ float Bs[16][68];
    const int tid = threadIdx.x;
    const int tx = tid & 15, ty = tid >> 4;
    const int m0 = blockIdx.x * 64, n0 = blockIdx.y * 64;
    const int lr = tid >> 2, lc4 = (tid & 3) * 4;
    const float* Ap = A + (size_t)(m0 + lr) * K + lc4;
    const float* Wp = W + (size_t)(n0 + lr) * K + lc4;
    float acc[4][4] = {};
    float4 av = *(const float4*)(Ap);
    float4 wv = *(const float4*)(Wp);
    for (int k0 = 0; k0 < K; k0 += 16) {
        __syncthreads();
        As[lc4 + 0][lr] = av.x; As[lc4 + 1][lr] = av.y;
        As[lc4 + 2][lr] = av.z; As[lc4 + 3][lr] = av.w;
        Bs[lc4 + 0][lr] = wv.x; Bs[lc4 + 1][lr] = wv.y;
        Bs[lc4 + 2][lr] = wv.z; Bs[lc4 + 3][lr] = wv.w;
        __syncthreads();
        if (k0 + 16 < K) {  // prefetch next tile while computing
            av = *(const float4*)(Ap + k0 + 16);
            wv = *(const float4*)(Wp + k0 + 16);
        }
#pragma unroll
        for (int k = 0; k < 16; ++k) {
            float a_[4], b_[4];
            float4 t = *(const float4*)&As[k][ty * 4];
            a_[0] = t.x; a_[1] = t.y; a_[2] = t.z; a_[3] = t.w;
            t = *(const float4*)&Bs[k][tx * 4];
            b_[0] = t.x; b_[1] = t.y; b_[2] = t.z; b_[3] = t.w;
#pragma unroll
            for (int i = 0; i < 4; ++i)
#pragma unroll
                for (int j = 0; j < 4; ++j)
                    acc[i][j] += a_[i] * b_[j];
        }
    }
    const float slope = *slope_p;
#pragma unroll
    for (int i = 0; i < 4; ++i) {
        const int row = m0 + ty * 4 + i;
        float4 r;
#pragma unroll
        for (int j = 0; j < 4; ++j) {
            float v = acc[i][j] + bias[n0 + tx * 4 + j];
            if (act) v = v > 0.f ? v : slope * v;
            (&r.x)[j] = v;
        }
        *(float4*)(C + (size_t)row * Nc + n0 + tx * 4) = r;
    }
}

// ---------------------------------------------------------------------------
// Per-row: es = softmax(E_row); u = es/||es||. Also accumulate
// s[64] = sum_i u_i  and  trace = sum_i (u_i . u_i)  for the analytic mean.
// One wave per row, 16 rows per wave, 64 rows per block.
// ---------------------------------------------------------------------------
__global__ __launch_bounds__(256) void row_softmax_u(
    const float* __restrict__ E, float* __restrict__ u, float* __restrict__ stats)
{
    const int w = threadIdx.x >> 6, lane = threadIdx.x & 63;
    __shared__ float sacc[4][64];
    __shared__ float tacc[4];
    float s_l = 0.f, t_w = 0.f;
    const int base = blockIdx.x * 64 + w * 16;
    for (int r = 0; r < 16; ++r) {
        const int row = base + r;
        float v = E[(size_t)row * 64 + lane];
        float mx = wave_max(v);
        float e = expf(v - mx);
        float tot = wave_sum(e);
        tot = __shfl(tot, 0, 64);
        float es = e / tot;
        float dd = wave_sum(es * es);
        dd = __shfl(dd, 0, 64);
        float uv = es / sqrtf(dd);  // max(.,1e-9) never binds: dd >= 1/64
        u[(size_t)row * 64 + lane] = uv;
        s_l += uv;
        float uu = wave_sum(uv * uv);
        if (lane == 0) t_w += uu;
    }
    sacc[w][lane] = s_l;
    if (lane == 0) tacc[w] = t_w;
    __syncthreads();
    if (threadIdx.x < 64) {
        float tot = sacc[0][threadIdx.x] + sacc[1][threadIdx.x] +
                    sacc[2][threadIdx.x] + sacc[3][threadIdx.x];
        atomicAdd(&stats[threadIdx.x], tot);
    }
    if (threadIdx.x == 0)
        atomicAdd(&stats[64], tacc[0] + tacc[1] + tacc[2] + tacc[3]);
}

// ---------------------------------------------------------------------------
// Max over off-diagonal of S = u u^T, upper-triangle tiles only (symmetry).
// ---------------------------------------------------------------------------
__global__ __launch_bounds__(256) void pass_max(
    const float* __restrict__ u, float* __restrict__ stats)
{
    const int bx = blockIdx.x, by = blockIdx.y;
    if (bx < by) return;  // lower triangle: whole block exits uniformly
    __shared__ float Ui[64][68], Uj[64][68];
    __shared__ float red[4];
    const int tid = threadIdx.x, tx = tid & 15, ty = tid >> 4;
    const int lr = tid >> 2, lc4 = (tid & 3) * 4;
    const float* uip = u + (size_t)(by * 64 + lr) * 64;
    const float* ujp = u + (size_t)(bx * 64 + lr) * 64;
#pragma unroll
    for (int it = 0; it < 4; ++it) {
        const int d0 = lc4 + it * 16;
        float4 v = *(const float4*)(uip + d0);
        Ui[d0 + 0][lr] = v.x; Ui[d0 + 1][lr] = v.y;
        Ui[d0 + 2][lr] = v.z; Ui[d0 + 3][lr] = v.w;
        v = *(const float4*)(ujp + d0);
        Uj[d0 + 0][lr] = v.x; Uj[d0 + 1][lr] = v.y;
        Uj[d0 + 2][lr] = v.z; Uj[d0 + 3][lr] = v.w;
    }
    __syncthreads();
    float s[4][4] = {};
#pragma unroll
    for (int d = 0; d < 64; ++d) {
        float a_[4], b_[4];
        float4 t = *(const float4*)&Ui[d][ty * 4];
        a_[0] = t.x; a_[1] = t.y; a_[2] = t.z; a_[3] = t.w;
        t = *(const float4*)&Uj[d][tx * 4];
        b_[0] = t.x; b_[1] = t.y; b_[2] = t.z; b_[3] = t.w;
#pragma unroll
        for (int i = 0; i < 4; ++i)
#pragma unroll
            for (int j = 0; j < 4; ++j)
                s[i][j] += a_[i] * b_[j];
    }
    float mx = 0.f;
    const int gi0 = by * 64 + ty * 4, gj0 = bx * 64 + tx * 4;
#pragma unroll
    for (int i = 0; i < 4; ++i)
#pragma unroll
        for (int j = 0; j < 4; ++j)
            if (gi0 + i != gj0 + j) mx = fmaxf(mx, s[i][j]);
    mx = wave_max(mx);
    if ((tid & 63) == 0) red[tid >> 6] = mx;
    __syncthreads();
    if (tid == 0) {
        float m4 = fmaxf(fmaxf(red[0], red[1]), fmaxf(red[2], red[3]));
        atomicMax((unsigned int*)&stats[65], __float_as_uint(m4));  // all S >= 0
    }
}

// m = (||s||^2 - trace) / N^2  (N^2 = 2^26, exact)
__global__ void fin_m(float* stats)
{
    float s = stats[threadIdx.x];
    float ss = wave_sum(s * s);
    if (threadIdx.x == 0)
        stats[66] = (ss - stats[64]) * (1.0f / 67108864.0f);
}

// ---------------------------------------------------------------------------
// Fused: recompute S tiles, transform -> lre, prelu(+/-), accumulate
// Lp = prelu(lre) @ E, Ln = prelu(-lre) @ E into per-js partials.
// Grid (128 row-tiles, 4 j-slices). LDS: Ut persists; Uj aliases the Ps/Ns
// region (S is in registers when Ps overwrites Uj).
// ---------------------------------------------------------------------------
__global__ __launch_bounds__(256) void pass_prop(
    const float* __restrict__ u, const float* __restrict__ E,
    const float* __restrict__ stats, const float* __restrict__ ah_p,
    float* __restrict__ Pp, float* __restrict__ Pn)
{
    __shared__ float Ut[64][68];
    __shared__ float R[2][64][68];  // R[0]: Uj then Ps; R[1]: Ns
    const int tid = threadIdx.x, tx = tid & 15, ty = tid >> 4;
    const int lr = tid >> 2, lc4 = (tid & 3) * 4;
    const int i0 = blockIdx.x * 64;
    const int js = blockIdx.y;
    const float m = stats[66];
    const float Mx = __uint_as_float(((const unsigned int*)stats)[65]);
    const float inv_pd = 1.f / (Mx - m);
    const float inv_m = 1.f / m;
    const float a = *ah_p;
    {
        const float* up = u + (size_t)(i0 + lr) * 64;
#pragma unroll
        for (int it = 0; it < 4; ++it) {
            const int d0 = lc4 + it * 16;
            float4 v = *(const float4*)(up + d0);
            Ut[d0 + 0][lr] = v.x; Ut[d0 + 1][lr] = v.y;
            Ut[d0 + 2][lr] = v.z; Ut[d0 + 3][lr] = v.w;
        }
    }
    float accP[4][4] = {}, accN[4][4] = {};
    for (int jt = 0; jt < 32; ++jt) {
        const int j0 = (js * 32 + jt) * 64;
        __syncthreads();  // prior iter's Ps/Ns reads done; Ut stores done (iter 0)
        {
            const float* up = u + (size_t)(j0 + lr) * 64;
#pragma unroll
            for (int it = 0; it < 4; ++it) {
                const int d0 = lc4 + it * 16;
                float4 v = *(const float4*)(up + d0);
                R[0][d0 + 0][lr] = v.x; R[0][d0 + 1][lr] = v.y;
                R[0][d0 + 2][lr] = v.z; R[0][d0 + 3][lr] = v.w;
            }
        }
        __syncthreads();
        float s[4][4] = {};
#pragma unroll
        for (int d = 0; d < 64; ++d) {
            float a_[4], b_[4];
            float4 t = *(const float4*)&Ut[d][ty * 4];
            a_[0] = t.x; a_[1] = t.y; a_[2] = t.z; a_[3] = t.w;
            t = *(const float4*)&R[0][d][tx * 4];
            b_[0] = t.x; b_[1] = t.y; b_[2] = t.z; b_[3] = t.w;
#pragma unroll
            for (int i = 0; i < 4; ++i)
#pragma unroll
                for (int j = 0; j < 4; ++j)
                    s[i][j] += a_[i] * b_[j];
        }
        __syncthreads();  // all reads of Uj done; safe to overwrite with Ps
#pragma unroll
        for (int i = 0; i < 4; ++i) {
            float4 pv, nv;
#pragma unroll
            for (int j = 0; j < 4; ++j) {
                const int gi = i0 + ty * 4 + i, gj = j0 + tx * 4 + j;
                const float S = s[i][j];
                const float sh = S - m;
                // replicate reference: else-branch is -((shifted + m) / m)
                float l = (sh > 0.f) ? sh * inv_pd : -((sh + m) * inv_m);
                if (gi == gj) l = 1.0f;  // diag: exact 0 then +eye
                float pos = l > 0.f ? l : a * l;
                float nl = -l;
                float neg = nl > 0.f ? nl : a * nl;
                (&pv.x)[j] = pos;
                (&nv.x)[j] = neg;
            }
            *(float4*)&R[0][ty * 4 + i][tx * 4] = pv;
            *(float4*)&R[1][ty * 4 + i][tx * 4] = nv;
        }
        __syncthreads();
#pragma unroll 4
        for (int jc = 0; jc < 16; ++jc) {
            float p_[4][4], n_[4][4], e_[4][4];
#pragma unroll
            for (int i = 0; i < 4; ++i) {
                float4 v = *(const float4*)&R[0][ty * 4 + i][jc * 4];
                p_[i][0] = v.x; p_[i][1] = v.y; p_[i][2] = v.z; p_[i][3] = v.w;
                v = *(const float4*)&R[1][ty * 4 + i][jc * 4];
                n_[i][0] = v.x; n_[i][1] = v.y; n_[i][2] = v.z; n_[i][3] = v.w;
            }
#pragma unroll
            for (int q = 0; q < 4; ++q) {
                float4 v = *(const float4*)(E + (size_t)(j0 + jc * 4 + q) * 64 + tx * 4);
                e_[q][0] = v.x; e_[q][1] = v.y; e_[q][2] = v.z; e_[q][3] = v.w;
            }
#pragma unroll
            for (int q = 0; q < 4; ++q)
#pragma unroll
                for (int i = 0; i < 4; ++i)
#pragma unroll
                    for (int c = 0; c < 4; ++c) {
                        accP[i][c] += p_[i][q] * e_[q][c];
                        accN[i][c] += n_[i][q] * e_[q][c];
                    }
        }
    }
#pragma unroll
    for (int i = 0; i < 4; ++i) {
        float4 pv, nv;
#pragma unroll
        for (int c = 0; c < 4; ++c) { (&pv.x)[c] = accP[i][c]; (&nv.x)[c] = accN[i][c]; }
        const size_t off = ((size_t)js * N + i0 + ty * 4 + i) * 64 + tx * 4;
        *(float4*)(Pp + off) = pv;
        *(float4*)(Pn + off) = nv;
    }
}

// Reduce 4 partials, row-softmax both, combine with E. One wave per row.
__global__ __launch_bounds__(256) void fin_msg(
    const float* __restrict__ Pp, const float* __restrict__ Pn,
    const float* __restrict__ E, float* __restrict__ outm)
{
    const int w = threadIdx.x >> 6, lane = threadIdx.x & 63;
    const int row = blockIdx.x * 4 + w;
    float lp = 0.f, ln = 0.f;
#pragma unroll
    for (int js = 0; js < 4; ++js) {
        lp += Pp[((size_t)js * N + row) * 64 + lane];
        ln += Pn[((size_t)js * N + row) * 64 + lane];
    }
    float mp = wave_max(lp);
    float ep = expf(lp - mp);
    float tp = wave_sum(ep); tp = __shfl(tp, 0, 64);
    float sp = ep / tp;
    float mn = wave_max(ln);
    float en = expf(ln - mn);
    float tn = wave_sum(en); tn = __shfl(tn, 0, 64);
    float sn = en / tn;
    outm[(size_t)row * 64 + lane] = (sp - sn + E[(size_t)row * 64 + lane]) * 0.5f;
}

__global__ void init_stats(float* stats)
{
    if (threadIdx.x < 128) stats[threadIdx.x] = 0.f;
}

extern "C" void kernel_launch(void* const* d_in, const int* in_sizes, int n_in,
                              void* d_out, int out_size, void* d_ws, size_t ws_size,
                              hipStream_t stream)
{
    const float* ori = (const float*)d_in[0];
    const float* smo = (const float*)d_in[1];
    // d_in[2] processed_feature: unused. d_in[3] universal_re: unused (beta=0).
    const float* Ws1 = (const float*)d_in[4];
    const float* bs1 = (const float*)d_in[5];
    const float* Ws2 = (const float*)d_in[6];
    const float* bs2 = (const float*)d_in[7];
    const float* Wl1 = (const float*)d_in[8];
    const float* bl1 = (const float*)d_in[9];
    const float* Wl2 = (const float*)d_in[10];
    const float* bl2 = (const float*)d_in[11];
    const float* Wh1 = (const float*)d_in[12];
    const float* bh1 = (const float*)d_in[13];
    const float* Wh2 = (const float*)d_in[14];
    const float* bh2 = (const float*)d_in[15];
    const float* am  = (const float*)d_in[16];
    const float* ah  = (const float*)d_in[17];

    float* out_ori = (float*)d_out;
    float* out_smo = out_ori + (size_t)N * 64;
    float* out_msg = out_smo + (size_t)N * 64;

    float* ws    = (float*)d_ws;
    float* h     = ws;                          // N*256
    float* E     = h  + (size_t)N * 256;        // N*64
    float* uu    = E  + (size_t)N * 64;         // N*64
    float* Pp    = uu + (size_t)N * 64;         // 4*N*64
    float* Pn    = Pp + (size_t)4 * N * 64;     // 4*N*64
    float* stats = Pn + (size_t)4 * N * 64;     // 128
    // total ~28 MB of d_ws

    const dim3 b(256);
    init_stats<<<1, 128, 0, stream>>>(stats);

    // smooth path
    gemm_bias_act<<<dim3(128, 4), b, 0, stream>>>(smo, Ws1, bs1, am, h, 256, 512, 1);
    gemm_bias_act<<<dim3(128, 1), b, 0, stream>>>(h, Ws2, bs2, am, out_smo, 64, 256, 0);
    // local path
    gemm_bias_act<<<dim3(128, 4), b, 0, stream>>>(ori, Wl1, bl1, am, h, 256, 128, 1);
    gemm_bias_act<<<dim3(128, 1), b, 0, stream>>>(h, Wl2, bl2, am, out_ori, 64, 256, 0);
    // hete path -> feature_emb E
    gemm_bias_act<<<dim3(128, 4), b, 0, stream>>>(smo, Wh1, bh1, ah, h, 256, 512, 1);
    gemm_bias_act<<<dim3(128, 1), b, 0, stream>>>(h, Wh2, bh2, ah, E, 64, 256, 0);

    row_softmax_u<<<128, b, 0, stream>>>(E, uu, stats);
    pass_max<<<dim3(128, 128), b, 0, stream>>>(uu, stats);
    fin_m<<<1, 64, 0, stream>>>(stats);
    pass_prop<<<dim3(128, 4), b, 0, stream>>>(uu, E, stats, ah, Pp, Pn);
    fin_msg<<<2048, b, 0, stream>>>(Pp, Pn, E, out_msg);
}

// Round 2
// 903.702 us; speedup vs baseline: 1.2567x; 1.2567x over previous
//
#include <hip/hip_runtime.h>
#include <hip/hip_bf16.h>

#define N 8192

typedef __attribute__((ext_vector_type(8))) short short8;
typedef __attribute__((ext_vector_type(4))) float f32x4;
typedef unsigned int uint;
typedef unsigned short ushort;

#define MFMA(a, b, c) __builtin_amdgcn_mfma_f32_16x16x32_bf16(a, b, c, 0, 0, 0)

union U8 { int4 i; short8 s; uint u[4]; };

__device__ __forceinline__ float wave_max(float v) {
#pragma unroll
    for (int o = 32; o > 0; o >>= 1) v = fmaxf(v, __shfl_xor(v, o, 64));
    return v;
}
__device__ __forceinline__ float wave_sum(float v) {
#pragma unroll
    for (int o = 32; o > 0; o >>= 1) v += __shfl_xor(v, o, 64);
    return v;
}

// RNE float -> bf16 bits (finite values only; no NaN in this pipeline)
__device__ __forceinline__ uint bf16_hi(float f) {
    uint u = __float_as_uint(f);
    return (u + 0x7fffu + ((u >> 16) & 1u)) >> 16;
}
// 2-way split: f ~= hi + lo, error ~2^-18 |f|
__device__ __forceinline__ uint2 bf16_split2(float f) {
    uint h = bf16_hi(f);
    float hf = __uint_as_float(h << 16);
    uint l = bf16_hi(f - hf);
    return make_uint2(h, l);
}
// 3-way split: f ~= h + m + l, error ~2^-27 |f|
__device__ __forceinline__ void bf16_split3(float f, uint& h, uint& m, uint& l) {
    h = bf16_hi(f);
    float hf = __uint_as_float(h << 16);
    float r1 = f - hf;            // exact
    m = bf16_hi(r1);
    float mf = __uint_as_float(m << 16);
    l = bf16_hi(r1 - mf);         // exact residual, rounded
}

__device__ __forceinline__ short8 ld_frag(const ushort* p) {
    U8 t; t.i = *(const int4*)p; return t.s;
}

// 8 packed u32 (hi|lo<<16) -> hi-frag and lo-frag short8
__device__ __forceinline__ void unpack_hl(int4 q0, int4 q1, short8& h, short8& l) {
    const uint* a = (const uint*)&q0;
    const uint* b = (const uint*)&q1;
    U8 hh, ll;
    hh.u[0] = (a[0] & 0xffffu) | (a[1] << 16);
    hh.u[1] = (a[2] & 0xffffu) | (a[3] << 16);
    hh.u[2] = (b[0] & 0xffffu) | (b[1] << 16);
    hh.u[3] = (b[2] & 0xffffu) | (b[3] << 16);
    ll.u[0] = (a[0] >> 16) | (a[1] & 0xffff0000u);
    ll.u[1] = (a[2] >> 16) | (a[3] & 0xffff0000u);
    ll.u[2] = (b[0] >> 16) | (b[1] & 0xffff0000u);
    ll.u[3] = (b[2] >> 16) | (b[3] & 0xffff0000u);
    h = hh.s; l = ll.s;
}

// ---------------------------------------------------------------------------
// fp32 MLP GEMM (unchanged from round 1): C = A @ W^T + bias, optional PReLU
// ---------------------------------------------------------------------------
__global__ __launch_bounds__(256) void gemm_bias_act(
    const float* __restrict__ A, const float* __restrict__ W,
    const float* __restrict__ bias, const float* __restrict__ slope_p,
    float* __restrict__ C, int Nc, int K, int act)
{
    __shared__ float As[16][68];
    __shared__ float Bs[16][68];
    const int tid = threadIdx.x;
    const int tx = tid & 15, ty = tid >> 4;
    const int m0 = blockIdx.x * 64, n0 = blockIdx.y * 64;
    const int lr = tid >> 2, lc4 = (tid & 3) * 4;
    const float* Ap = A + (size_t)(m0 + lr) * K + lc4;
    const float* Wp = W + (size_t)(n0 + lr) * K + lc4;
    float acc[4][4] = {};
    float4 av = *(const float4*)(Ap);
    float4 wv = *(const float4*)(Wp);
    for (int k0 = 0; k0 < K; k0 += 16) {
        __syncthreads();
        As[lc4 + 0][lr] = av.x; As[lc4 + 1][lr] = av.y;
        As[lc4 + 2][lr] = av.z; As[lc4 + 3][lr] = av.w;
        Bs[lc4 + 0][lr] = wv.x; Bs[lc4 + 1][lr] = wv.y;
        Bs[lc4 + 2][lr] = wv.z; Bs[lc4 + 3][lr] = wv.w;
        __syncthreads();
        if (k0 + 16 < K) {
            av = *(const float4*)(Ap + k0 + 16);
            wv = *(const float4*)(Wp + k0 + 16);
        }
#pragma unroll
        for (int k = 0; k < 16; ++k) {
            float a_[4], b_[4];
            float4 t = *(const float4*)&As[k][ty * 4];
            a_[0] = t.x; a_[1] = t.y; a_[2] = t.z; a_[3] = t.w;
            t = *(const float4*)&Bs[k][tx * 4];
            b_[0] = t.x; b_[1] = t.y; b_[2] = t.z; b_[3] = t.w;
#pragma unroll
            for (int i = 0; i < 4; ++i)
#pragma unroll
                for (int j = 0; j < 4; ++j)
                    acc[i][j] += a_[i] * b_[j];
        }
    }
    const float slope = *slope_p;
#pragma unroll
    for (int i = 0; i < 4; ++i) {
        const int row = m0 + ty * 4 + i;
        float4 r;
#pragma unroll
        for (int j = 0; j < 4; ++j) {
            float v = acc[i][j] + bias[n0 + tx * 4 + j];
            if (act) v = v > 0.f ? v : slope * v;
            (&r.x)[j] = v;
        }
        *(float4*)(C + (size_t)row * Nc + n0 + tx * 4) = r;
    }
}

// ---------------------------------------------------------------------------
// Row softmax + normalize; emit 3-way bf16 split of u; accumulate s, trace.
// ---------------------------------------------------------------------------
__global__ __launch_bounds__(256) void row_softmax_u(
    const float* __restrict__ E, ushort* __restrict__ uh, ushort* __restrict__ um,
    ushort* __restrict__ ul, float* __restrict__ stats)
{
    const int w = threadIdx.x >> 6, lane = threadIdx.x & 63;
    __shared__ float sacc[4][64];
    __shared__ float tacc[4];
    float s_l = 0.f, t_w = 0.f;
    const int base = blockIdx.x * 64 + w * 16;
    for (int r = 0; r < 16; ++r) {
        const int row = base + r;
        float v = E[(size_t)row * 64 + lane];
        float mx = wave_max(v);
        float e = expf(v - mx);
        float tot = wave_sum(e);
        tot = __shfl(tot, 0, 64);
        float es = e / tot;
        float dd = wave_sum(es * es);
        dd = __shfl(dd, 0, 64);
        float uv = es / sqrtf(dd);   // max(.,1e-9) never binds: dd >= 1/64
        uint h, m, l;
        bf16_split3(uv, h, m, l);
        const size_t idx = (size_t)row * 64 + lane;
        uh[idx] = (ushort)h; um[idx] = (ushort)m; ul[idx] = (ushort)l;
        s_l += uv;
        float uu = wave_sum(uv * uv);
        if (lane == 0) t_w += uu;
    }
    sacc[w][lane] = s_l;
    if (lane == 0) tacc[w] = t_w;
    __syncthreads();
    if (threadIdx.x < 64) {
        float tot = sacc[0][threadIdx.x] + sacc[1][threadIdx.x] +
                    sacc[2][threadIdx.x] + sacc[3][threadIdx.x];
        atomicAdd(&stats[threadIdx.x], tot);
    }
    if (threadIdx.x == 0)
        atomicAdd(&stats[64], tacc[0] + tacc[1] + tacc[2] + tacc[3]);
}

// ---------------------------------------------------------------------------
// Transpose E -> Et hi/lo bf16 [64][8192] so PV B-frags are 16B loads.
// ---------------------------------------------------------------------------
__global__ __launch_bounds__(256) void trans_e(
    const float* __restrict__ E, ushort* __restrict__ Eth, ushort* __restrict__ Etl)
{
    __shared__ ushort Th[64][72];
    __shared__ ushort Tl[64][72];
    const int ib = blockIdx.x;
    const int r = threadIdx.x >> 2;
    const int c0 = (threadIdx.x & 3) * 16;
#pragma unroll
    for (int q = 0; q < 4; ++q) {
        float4 v = *(const float4*)(E + (size_t)(ib * 64 + r) * 64 + c0 + q * 4);
#pragma unroll
        for (int t = 0; t < 4; ++t) {
            uint2 hl = bf16_split2((&v.x)[t]);
            Th[c0 + q * 4 + t][r] = (ushort)hl.x;
            Tl[c0 + q * 4 + t][r] = (ushort)hl.y;
        }
    }
    __syncthreads();
    const int c = threadIdx.x >> 2;
    const int j0 = (threadIdx.x & 3) * 16;
    const size_t go = (size_t)c * N + ib * 64 + j0;
    *(int4*)(Eth + go)     = *(const int4*)&Th[c][j0];
    *(int4*)(Eth + go + 8) = *(const int4*)&Th[c][j0 + 8];
    *(int4*)(Etl + go)     = *(const int4*)&Tl[c][j0];
    *(int4*)(Etl + go + 8) = *(const int4*)&Tl[c][j0 + 8];
}

// ---------------------------------------------------------------------------
// S = u u^T via 6-term 3-way-split MFMA (delta_S ~ 1e-7 — flip-safe).
// Max over off-diagonal, upper-triangle tiles only.
// ---------------------------------------------------------------------------
__global__ __launch_bounds__(256) void pass_max_mfma(
    const ushort* __restrict__ uh, const ushort* __restrict__ um,
    const ushort* __restrict__ ul, float* __restrict__ stats)
{
    const int bx = blockIdx.x, by = blockIdx.y;
    if (bx < by) return;
    const int w = threadIdx.x >> 6, lane = threadIdx.x & 63;
    const int l16 = lane & 15, lg = lane >> 4;
    const size_t ao = (size_t)(by * 64 + w * 16 + l16) * 64 + lg * 8;
    short8 Ah0 = ld_frag(uh + ao), Ah1 = ld_frag(uh + ao + 32);
    short8 Am0 = ld_frag(um + ao), Am1 = ld_frag(um + ao + 32);
    short8 Al0 = ld_frag(ul + ao), Al1 = ld_frag(ul + ao + 32);
    float mx = 0.f;
    const int i0 = by * 64 + w * 16 + lg * 4;
    for (int jn = 0; jn < 4; ++jn) {
        const size_t bo = (size_t)(bx * 64 + jn * 16 + l16) * 64 + lg * 8;
        short8 Bh0 = ld_frag(uh + bo), Bh1 = ld_frag(uh + bo + 32);
        short8 Bm0 = ld_frag(um + bo), Bm1 = ld_frag(um + bo + 32);
        short8 Bl0 = ld_frag(ul + bo), Bl1 = ld_frag(ul + bo + 32);
        f32x4 acc = {0.f, 0.f, 0.f, 0.f};
        acc = MFMA(Ah0, Bl0, acc); acc = MFMA(Ah1, Bl1, acc);  // h*l
        acc = MFMA(Al0, Bh0, acc); acc = MFMA(Al1, Bh1, acc);  // l*h
        acc = MFMA(Am0, Bm0, acc); acc = MFMA(Am1, Bm1, acc);  // m*m
        acc = MFMA(Ah0, Bm0, acc); acc = MFMA(Ah1, Bm1, acc);  // h*m
        acc = MFMA(Am0, Bh0, acc); acc = MFMA(Am1, Bh1, acc);  // m*h
        acc = MFMA(Ah0, Bh0, acc); acc = MFMA(Ah1, Bh1, acc);  // h*h
        const int j = bx * 64 + jn * 16 + l16;
#pragma unroll
        for (int r = 0; r < 4; ++r)
            if (i0 + r != j) mx = fmaxf(mx, acc[r]);
    }
    mx = wave_max(mx);
    __shared__ float red[4];
    if (lane == 0) red[w] = mx;
    __syncthreads();
    if (threadIdx.x == 0)
        atomicMax((uint*)&stats[65],
                  __float_as_uint(fmaxf(fmaxf(red[0], red[1]), fmaxf(red[2], red[3]))));
}

// m = (||s||^2 - trace) / N^2
__global__ void fin_m(float* stats)
{
    float s = stats[threadIdx.x];
    float ss = wave_sum(s * s);
    if (threadIdx.x == 0)
        stats[66] = (ss - stats[64]) * (1.0f / 67108864.0f);
}

// ---------------------------------------------------------------------------
// Fused: S tile (6-term MFMA) -> transform -> P,N 2-way split -> wave-private
// LDS round-trip -> PV via 3-term MFMA against Et hi/lo. NO barriers.
// Grid (128 i-tiles, 4 j-slices); each wave owns 16 i-rows.
// ---------------------------------------------------------------------------
__global__ __launch_bounds__(256, 2) void pass_prop_mfma(
    const ushort* __restrict__ uh, const ushort* __restrict__ um,
    const ushort* __restrict__ ul, const ushort* __restrict__ Eth,
    const ushort* __restrict__ Etl, const float* __restrict__ stats,
    const float* __restrict__ ah_p, float* __restrict__ Pp, float* __restrict__ Pn)
{
    __shared__ uint Plds[4][16][68];   // packed (hi | lo<<16), stride 68: <=2-way conflicts
    __shared__ uint Nlds[4][16][68];
    const int w = threadIdx.x >> 6, lane = threadIdx.x & 63;
    const int l16 = lane & 15, lg = lane >> 4;
    const int ib = blockIdx.x, js = blockIdx.y;
    const float m = stats[66];
    const float Mx = __uint_as_float(((const uint*)stats)[65]);
    const float inv_pd = 1.f / (Mx - m);
    const float inv_m = 1.f / m;
    const float a = *ah_p;
    const size_t ao = (size_t)(ib * 64 + w * 16 + l16) * 64 + lg * 8;
    const short8 Ah0 = ld_frag(uh + ao), Ah1 = ld_frag(uh + ao + 32);
    const short8 Am0 = ld_frag(um + ao), Am1 = ld_frag(um + ao + 32);
    const short8 Al0 = ld_frag(ul + ao), Al1 = ld_frag(ul + ao + 32);
    const int irow0 = ib * 64 + w * 16 + lg * 4;
    f32x4 accP[4], accN[4];
#pragma unroll
    for (int cs = 0; cs < 4; ++cs) {
        accP[cs] = (f32x4){0.f, 0.f, 0.f, 0.f};
        accN[cs] = (f32x4){0.f, 0.f, 0.f, 0.f};
    }
    for (int jt = 0; jt < 32; ++jt) {
        const int j0 = (js * 32 + jt) * 64;
        // ---- S tiles + transform + split into wave-private LDS ----
        for (int jn = 0; jn < 4; ++jn) {
            const size_t bo = (size_t)(j0 + jn * 16 + l16) * 64 + lg * 8;
            short8 Bh0 = ld_frag(uh + bo), Bh1 = ld_frag(uh + bo + 32);
            short8 Bm0 = ld_frag(um + bo), Bm1 = ld_frag(um + bo + 32);
            short8 Bl0 = ld_frag(ul + bo), Bl1 = ld_frag(ul + bo + 32);
            f32x4 s = {0.f, 0.f, 0.f, 0.f};
            s = MFMA(Ah0, Bl0, s); s = MFMA(Ah1, Bl1, s);
            s = MFMA(Al0, Bh0, s); s = MFMA(Al1, Bh1, s);
            s = MFMA(Am0, Bm0, s); s = MFMA(Am1, Bm1, s);
            s = MFMA(Ah0, Bm0, s); s = MFMA(Ah1, Bm1, s);
            s = MFMA(Am0, Bh0, s); s = MFMA(Am1, Bh1, s);
            s = MFMA(Ah0, Bh0, s); s = MFMA(Ah1, Bh1, s);
            const int j = j0 + jn * 16 + l16;
#pragma unroll
            for (int r = 0; r < 4; ++r) {
                const float sh = s[r] - m;
                float l = (sh > 0.f) ? sh * inv_pd : -((sh + m) * inv_m);
                if (irow0 + r == j) l = 1.0f;  // diag: exact 0 then +eye
                float pos = l > 0.f ? l : a * l;
                float nl = -l;
                float neg = nl > 0.f ? nl : a * nl;
                uint2 hp = bf16_split2(pos);
                uint2 hn = bf16_split2(neg);
                Plds[w][lg * 4 + r][jn * 16 + l16] = hp.x | (hp.y << 16);
                Nlds[w][lg * 4 + r][jn * 16 + l16] = hn.x | (hn.y << 16);
            }
        }
        // ---- PV: wave reads only its own LDS region (no barrier needed) ----
#pragma unroll
        for (int kc = 0; kc < 2; ++kc) {
            const uint* pr = &Plds[w][l16][kc * 32 + lg * 8];
            short8 PhA, PlA;
            unpack_hl(*(const int4*)pr, *(const int4*)(pr + 4), PhA, PlA);
            const uint* nr = &Nlds[w][l16][kc * 32 + lg * 8];
            short8 NhA, NlA;
            unpack_hl(*(const int4*)nr, *(const int4*)(nr + 4), NhA, NlA);
            const int ecol = j0 + kc * 32 + lg * 8;
#pragma unroll
            for (int cs = 0; cs < 4; ++cs) {
                const size_t eo = (size_t)(cs * 16 + l16) * N + ecol;
                short8 Eh = ld_frag(Eth + eo);
                short8 El = ld_frag(Etl + eo);
                accP[cs] = MFMA(PlA, Eh, accP[cs]);
                accP[cs] = MFMA(PhA, El, accP[cs]);
                accP[cs] = MFMA(PhA, Eh, accP[cs]);
                accN[cs] = MFMA(NlA, Eh, accN[cs]);
                accN[cs] = MFMA(NhA, El, accN[cs]);
                accN[cs] = MFMA(NhA, Eh, accN[cs]);
            }
        }
    }
#pragma unroll
    for (int cs = 0; cs < 4; ++cs)
#pragma unroll
        for (int r = 0; r < 4; ++r) {
            const size_t row = irow0 + r;
            const size_t col = cs * 16 + l16;
            Pp[((size_t)js * N + row) * 64 + col] = accP[cs][r];
            Pn[((size_t)js * N + row) * 64 + col] = accN[cs][r];
        }
}

// Reduce 4 partials, row-softmax both, combine with fp32 E.
__global__ __launch_bounds__(256) void fin_msg(
    const float* __restrict__ Pp, const float* __restrict__ Pn,
    const float* __restrict__ E, float* __restrict__ outm)
{
    const int w = threadIdx.x >> 6, lane = threadIdx.x & 63;
    const int row = blockIdx.x * 4 + w;
    float lp = 0.f, ln = 0.f;
#pragma unroll
    for (int js = 0; js < 4; ++js) {
        lp += Pp[((size_t)js * N + row) * 64 + lane];
        ln += Pn[((size_t)js * N + row) * 64 + lane];
    }
    float mp = wave_max(lp);
    float ep = expf(lp - mp);
    float tp = wave_sum(ep); tp = __shfl(tp, 0, 64);
    float sp = ep / tp;
    float mn = wave_max(ln);
    float en = expf(ln - mn);
    float tn = wave_sum(en); tn = __shfl(tn, 0, 64);
    float sn = en / tn;
    outm[(size_t)row * 64 + lane] = (sp - sn + E[(size_t)row * 64 + lane]) * 0.5f;
}

__global__ void init_stats(float* stats)
{
    if (threadIdx.x < 128) stats[threadIdx.x] = 0.f;
}

extern "C" void kernel_launch(void* const* d_in, const int* in_sizes, int n_in,
                              void* d_out, int out_size, void* d_ws, size_t ws_size,
                              hipStream_t stream)
{
    const float* ori = (const float*)d_in[0];
    const float* smo = (const float*)d_in[1];
    // d_in[2] processed_feature: unused. d_in[3] universal_re: unused (beta=0).
    const float* Ws1 = (const float*)d_in[4];
    const float* bs1 = (const float*)d_in[5];
    const float* Ws2 = (const float*)d_in[6];
    const float* bs2 = (const float*)d_in[7];
    const float* Wl1 = (const float*)d_in[8];
    const float* bl1 = (const float*)d_in[9];
    const float* Wl2 = (const float*)d_in[10];
    const float* bl2 = (const float*)d_in[11];
    const float* Wh1 = (const float*)d_in[12];
    const float* bh1 = (const float*)d_in[13];
    const float* Wh2 = (const float*)d_in[14];
    const float* bh2 = (const float*)d_in[15];
    const float* am  = (const float*)d_in[16];
    const float* ah  = (const float*)d_in[17];

    float* out_ori = (float*)d_out;
    float* out_smo = out_ori + (size_t)N * 64;
    float* out_msg = out_smo + (size_t)N * 64;

    char* p = (char*)d_ws;
    float* h   = (float*)p;  p += (size_t)N * 256 * 4;   // 8 MB
    float* E   = (float*)p;  p += (size_t)N * 64 * 4;    // 2 MB
    float* Pp  = (float*)p;  p += (size_t)4 * N * 64 * 4; // 8 MB
    float* Pn  = (float*)p;  p += (size_t)4 * N * 64 * 4; // 8 MB
    ushort* uh  = (ushort*)p; p += (size_t)N * 64 * 2;   // 1 MB
    ushort* um  = (ushort*)p; p += (size_t)N * 64 * 2;
    ushort* ul  = (ushort*)p; p += (size_t)N * 64 * 2;
    ushort* Eth = (ushort*)p; p += (size_t)N * 64 * 2;
    ushort* Etl = (ushort*)p; p += (size_t)N * 64 * 2;
    float* stats = (float*)p;                            // 128 floats

    const dim3 b(256);
    init_stats<<<1, 128, 0, stream>>>(stats);

    // smooth path
    gemm_bias_act<<<dim3(128, 4), b, 0, stream>>>(smo, Ws1, bs1, am, h, 256, 512, 1);
    gemm_bias_act<<<dim3(128, 1), b, 0, stream>>>(h, Ws2, bs2, am, out_smo, 64, 256, 0);
    // local path
    gemm_bias_act<<<dim3(128, 4), b, 0, stream>>>(ori, Wl1, bl1, am, h, 256, 128, 1);
    gemm_bias_act<<<dim3(128, 1), b, 0, stream>>>(h, Wl2, bl2, am, out_ori, 64, 256, 0);
    // hete path -> feature_emb E
    gemm_bias_act<<<dim3(128, 4), b, 0, stream>>>(smo, Wh1, bh1, ah, h, 256, 512, 1);
    gemm_bias_act<<<dim3(128, 1), b, 0, stream>>>(h, Wh2, bh2, ah, E, 64, 256, 0);

    row_softmax_u<<<128, b, 0, stream>>>(E, uh, um, ul, stats);
    trans_e<<<128, b, 0, stream>>>(E, Eth, Etl);
    pass_max_mfma<<<dim3(128, 128), b, 0, stream>>>(uh, um, ul, stats);
    fin_m<<<1, 64, 0, stream>>>(stats);
    pass_prop_mfma<<<dim3(128, 4), b, 0, stream>>>(uh, um, ul, Eth, Etl, stats, ah, Pp, Pn);
    fin_msg<<<2048, b, 0, stream>>>(Pp, Pn, E, out_msg);
}

// Round 6
// 744.151 us; speedup vs baseline: 1.5262x; 1.2144x over previous
//
#include <hip/hip_runtime.h>
#include <hip/hip_bf16.h>

#define N 8192

typedef _Float16 half_t;
typedef __attribute__((ext_vector_type(8))) _Float16 half8;
typedef __attribute__((ext_vector_type(4))) float f32x4;
typedef unsigned int uint;
typedef unsigned short ushort;

#define MFMA16(a, b, c) __builtin_amdgcn_mfma_f32_16x16x32_f16(a, b, c, 0, 0, 0)

// residual scale: u = uh + ul * 2^-11 (ul stored x2048 to stay f16-normal)
#define RES_SCALE 2048.0f
#define RES_INV   (1.0f / 2048.0f)

union UH8 { int4 i; half8 h; };
__device__ __forceinline__ half8 ldh(const ushort* p) {
    UH8 t; t.i = *(const int4*)p; return t.h;
}
__device__ __forceinline__ ushort h2u(half_t h) {
    union { half_t f; ushort u; } c; c.f = h; return c.u;
}

__device__ __forceinline__ float wave_max(float v) {
#pragma unroll
    for (int o = 32; o > 0; o >>= 1) v = fmaxf(v, __shfl_xor(v, o, 64));
    return v;
}
__device__ __forceinline__ float wave_sum(float v) {
#pragma unroll
    for (int o = 32; o > 0; o >>= 1) v += __shfl_xor(v, o, 64);
    return v;
}

// ---------------------------------------------------------------------------
// fp32 MLP GEMM: C[M x Nc] = A[M x K] @ W[Nc x K]^T + bias, optional PReLU.
// (kept fp32: hete path feeds the flip-sensitive S computation)
// ---------------------------------------------------------------------------
__global__ __launch_bounds__(256) void gemm_bias_act(
    const float* __restrict__ A, const float* __restrict__ W,
    const float* __restrict__ bias, const float* __restrict__ slope_p,
    float* __restrict__ C, int Nc, int K, int act)
{
    __shared__ float As[16][68];
    __shared__ float Bs[16][68];
    const int tid = threadIdx.x;
    const int tx = tid & 15, ty = tid >> 4;
    const int m0 = blockIdx.x * 64, n0 = blockIdx.y * 64;
    const int lr = tid >> 2, lc4 = (tid & 3) * 4;
    const float* Ap = A + (size_t)(m0 + lr) * K + lc4;
    const float* Wp = W + (size_t)(n0 + lr) * K + lc4;
    float acc[4][4] = {};
    float4 av = *(const float4*)(Ap);
    float4 wv = *(const float4*)(Wp);
    for (int k0 = 0; k0 < K; k0 += 16) {
        __syncthreads();
        As[lc4 + 0][lr] = av.x; As[lc4 + 1][lr] = av.y;
        As[lc4 + 2][lr] = av.z; As[lc4 + 3][lr] = av.w;
        Bs[lc4 + 0][lr] = wv.x; Bs[lc4 + 1][lr] = wv.y;
        Bs[lc4 + 2][lr] = wv.z; Bs[lc4 + 3][lr] = wv.w;
        __syncthreads();
        if (k0 + 16 < K) {
            av = *(const float4*)(Ap + k0 + 16);
            wv = *(const float4*)(Wp + k0 + 16);
        }
#pragma unroll
        for (int k = 0; k < 16; ++k) {
            float a_[4], b_[4];
            float4 t = *(const float4*)&As[k][ty * 4];
            a_[0] = t.x; a_[1] = t.y; a_[2] = t.z; a_[3] = t.w;
            t = *(const float4*)&Bs[k][tx * 4];
            b_[0] = t.x; b_[1] = t.y; b_[2] = t.z; b_[3] = t.w;
#pragma unroll
            for (int i = 0; i < 4; ++i)
#pragma unroll
                for (int j = 0; j < 4; ++j)
                    acc[i][j] += a_[i] * b_[j];
        }
    }
    const float slope = *slope_p;
#pragma unroll
    for (int i = 0; i < 4; ++i) {
        const int row = m0 + ty * 4 + i;
        float4 r;
#pragma unroll
        for (int j = 0; j < 4; ++j) {
            float v = acc[i][j] + bias[n0 + tx * 4 + j];
            if (act) v = v > 0.f ? v : slope * v;
            (&r.x)[j] = v;
        }
        *(float4*)(C + (size_t)row * Nc + n0 + tx * 4) = r;
    }
}

// ---------------------------------------------------------------------------
// Row softmax + normalize; emit f16 2-way split of u (residual x2048);
// accumulate s[64] and trace for the analytic mean. 512 blocks, 4 rows/wave.
// ---------------------------------------------------------------------------
__global__ __launch_bounds__(256) void row_softmax_u(
    const float* __restrict__ E, ushort* __restrict__ uh, ushort* __restrict__ ul,
    float* __restrict__ stats)
{
    const int w = threadIdx.x >> 6, lane = threadIdx.x & 63;
    __shared__ float sacc[4][64];
    __shared__ float tacc[4];
    float s_l = 0.f, t_w = 0.f;
    const int base = blockIdx.x * 16 + w * 4;
    for (int r = 0; r < 4; ++r) {
        const int row = base + r;
        float v = E[(size_t)row * 64 + lane];
        float mx = wave_max(v);
        float e = expf(v - mx);
        float tot = wave_sum(e);
        tot = __shfl(tot, 0, 64);
        float es = e / tot;
        float dd = wave_sum(es * es);
        dd = __shfl(dd, 0, 64);
        float uv = es / sqrtf(dd);   // max(.,1e-9) never binds: dd >= 1/64
        half_t h = (half_t)uv;
        half_t l = (half_t)((uv - (float)h) * RES_SCALE);
        const size_t idx = (size_t)row * 64 + lane;
        uh[idx] = h2u(h); ul[idx] = h2u(l);
        s_l += uv;
        float uu = wave_sum(uv * uv);
        if (lane == 0) t_w += uu;
    }
    sacc[w][lane] = s_l;
    if (lane == 0) tacc[w] = t_w;
    __syncthreads();
    if (threadIdx.x < 64) {
        float tot = sacc[0][threadIdx.x] + sacc[1][threadIdx.x] +
                    sacc[2][threadIdx.x] + sacc[3][threadIdx.x];
        atomicAdd(&stats[threadIdx.x], tot);
    }
    if (threadIdx.x == 0)
        atomicAdd(&stats[64], tacc[0] + tacc[1] + tacc[2] + tacc[3]);
}

// ---------------------------------------------------------------------------
// Transpose E -> Et f16 [64][8192] so PV B-frags are direct 16B loads.
// ---------------------------------------------------------------------------
__global__ __launch_bounds__(256) void trans_e(
    const float* __restrict__ E, ushort* __restrict__ Et)
{
    __shared__ ushort T[64][72];
    const int ib = blockIdx.x;
    const int r = threadIdx.x >> 2;
    const int c0 = (threadIdx.x & 3) * 16;
#pragma unroll
    for (int q = 0; q < 4; ++q) {
        float4 v = *(const float4*)(E + (size_t)(ib * 64 + r) * 64 + c0 + q * 4);
#pragma unroll
        for (int t = 0; t < 4; ++t)
            T[c0 + q * 4 + t][r] = h2u((half_t)((&v.x)[t]));
    }
    __syncthreads();
    const int c = threadIdx.x >> 2;
    const int j0 = (threadIdx.x & 3) * 16;
    const size_t go = (size_t)c * N + ib * 64 + j0;
    *(int4*)(Et + go)     = *(const int4*)&T[c][j0];
    *(int4*)(Et + go + 8) = *(const int4*)&T[c][j0 + 8];
}

// ---------------------------------------------------------------------------
// Max over off-diagonal of S = u u^T. 1-wave blocks, 16-row i-strip x 1024-col
// j-group, upper-triangle skip. Per-block partial max -> maxbuf (no atomics).
// S = hh + 2^-11 (h l' + l' h)  via f16 MFMA, delta_S ~ 3e-8 (flip-safe).
// ---------------------------------------------------------------------------
__global__ __launch_bounds__(64) void pass_max_f16(
    const ushort* __restrict__ uh, const ushort* __restrict__ ul,
    float* __restrict__ maxbuf)
{
    const int bx = blockIdx.x;       // i-strip [0,512)
    const int by = blockIdx.y;       // j-group [0,8)
    const int bid = by * 512 + bx;
    const int i0 = bx * 16;
    const int lane = threadIdx.x;
    const int l16 = lane & 15, lg = lane >> 4;
    if (by * 1024 + 1024 <= i0) {    // entire group below diagonal
        if (lane == 0) maxbuf[bid] = 0.f;
        return;
    }
    const size_t ao = (size_t)(i0 + l16) * 64 + lg * 8;
    const half8 Ah0 = ldh(uh + ao), Ah1 = ldh(uh + ao + 32);
    const half8 Al0 = ldh(ul + ao), Al1 = ldh(ul + ao + 32);
    float mx = 0.f;
    for (int jn = 0; jn < 64; ++jn) {
        const int j0 = by * 1024 + jn * 16;
        if (j0 + 16 <= i0) continue;   // tile fully below diagonal
        const size_t bo = (size_t)(j0 + l16) * 64 + lg * 8;
        half8 Bh0 = ldh(uh + bo), Bh1 = ldh(uh + bo + 32);
        half8 Bl0 = ldh(ul + bo), Bl1 = ldh(ul + bo + 32);
        f32x4 s1 = {0.f, 0.f, 0.f, 0.f};
        f32x4 s2 = {0.f, 0.f, 0.f, 0.f};
        s1 = MFMA16(Ah0, Bh0, s1); s1 = MFMA16(Ah1, Bh1, s1);
        s2 = MFMA16(Ah0, Bl0, s2); s2 = MFMA16(Ah1, Bl1, s2);
        s2 = MFMA16(Al0, Bh0, s2); s2 = MFMA16(Al1, Bh1, s2);
        const bool dt = (j0 == i0);
#pragma unroll
        for (int r = 0; r < 4; ++r) {
            float s = fmaf(s2[r], RES_INV, s1[r]);
            bool dg = dt && (lg * 4 + r == l16);
            mx = dg ? mx : fmaxf(mx, s);
        }
    }
    mx = wave_max(mx);
    if (lane == 0) maxbuf[bid] = mx;
}

// Reduce block maxes -> M; m = (||s||^2 - trace) / N^2.
__global__ __launch_bounds__(256) void fin_m(
    const float* __restrict__ maxbuf, float* __restrict__ stats)
{
    const int t = threadIdx.x;
    float mx = 0.f;
    for (int i = t; i < 4096; i += 256) mx = fmaxf(mx, maxbuf[i]);
    mx = wave_max(mx);
    __shared__ float red[4];
    __shared__ float ssh;
    if ((t & 63) == 0) red[t >> 6] = mx;
    if (t < 64) {
        float s = stats[t];
        float ss = wave_sum(s * s);
        if (t == 0) ssh = ss;
    }
    __syncthreads();
    if (t == 0) {
        stats[65] = fmaxf(fmaxf(red[0], red[1]), fmaxf(red[2], red[3]));
        stats[66] = (ssh - stats[64]) * (1.0f / 67108864.0f);
    }
}

// ---------------------------------------------------------------------------
// Fused: S tiles (f16 split MFMA) -> transform -> P,N f16 -> wave-private LDS
// -> PV (plain f16 MFMA vs Et). Block = one 16-row i-tile x one js slice;
// 4 waves split the 32 jt, deterministic LDS combine at the end.
// ---------------------------------------------------------------------------
__global__ __launch_bounds__(256, 4) void pass_prop_f16(
    const ushort* __restrict__ uh, const ushort* __restrict__ ul,
    const ushort* __restrict__ Et, const float* __restrict__ stats,
    const float* __restrict__ ah_p, float* __restrict__ Pp, float* __restrict__ Pn)
{
    __shared__ ushort PNs[4][2][16][68];   // [wave][P/N][i-local][j-local], stride 68
    const int w = threadIdx.x >> 6, lane = threadIdx.x & 63;
    const int l16 = lane & 15, lg = lane >> 4;
    const int i0 = blockIdx.x * 16;
    const int js = blockIdx.y;
    const float m = stats[66];
    const float Mx = stats[65];
    const float inv_pd = 1.f / (Mx - m);
    const float c1 = -m * inv_pd;
    const float ninv_m = -1.f / m;
    const float a = *ah_p;
    const size_t ao = (size_t)(i0 + l16) * 64 + lg * 8;
    const half8 Ah0 = ldh(uh + ao), Ah1 = ldh(uh + ao + 32);
    const half8 Al0 = ldh(ul + ao), Al1 = ldh(ul + ao + 32);
    f32x4 accP[4], accN[4];
#pragma unroll
    for (int cs = 0; cs < 4; ++cs) {
        accP[cs] = (f32x4){0.f, 0.f, 0.f, 0.f};
        accN[cs] = (f32x4){0.f, 0.f, 0.f, 0.f};
    }
    ushort (*myP)[68] = PNs[w][0];
    ushort (*myN)[68] = PNs[w][1];
    for (int t = 0; t < 8; ++t) {
        const int j0 = (js * 32 + t * 4 + w) * 64;
        // ---- S tiles -> transform -> f16 P,N into wave-private LDS ----
#pragma unroll
        for (int jn = 0; jn < 4; ++jn) {
            const size_t bo = (size_t)(j0 + jn * 16 + l16) * 64 + lg * 8;
            half8 Bh0 = ldh(uh + bo), Bh1 = ldh(uh + bo + 32);
            half8 Bl0 = ldh(ul + bo), Bl1 = ldh(ul + bo + 32);
            f32x4 s1 = {0.f, 0.f, 0.f, 0.f};
            f32x4 s2 = {0.f, 0.f, 0.f, 0.f};
            s1 = MFMA16(Ah0, Bh0, s1); s1 = MFMA16(Ah1, Bh1, s1);
            s2 = MFMA16(Ah0, Bl0, s2); s2 = MFMA16(Ah1, Bl1, s2);
            s2 = MFMA16(Al0, Bh0, s2); s2 = MFMA16(Al1, Bh1, s2);
            const bool dt = (j0 + jn * 16 == i0);
#pragma unroll
            for (int r = 0; r < 4; ++r) {
                float s = fmaf(s2[r], RES_INV, s1[r]);
                // l = (s-m > 0) ? (s-m)/(M-m) : -(s/m)
                float l = (s > m) ? fmaf(s, inv_pd, c1) : s * ninv_m;
                if (dt && (lg * 4 + r == l16)) l = 1.0f;  // diag: exact 0 then +eye
                float q = a * l;
                bool gp = l > 0.f;
                float pos = gp ? l : q;
                float neg = -(gp ? q : l);
                myP[lg * 4 + r][jn * 16 + l16] = h2u((half_t)pos);
                myN[lg * 4 + r][jn * 16 + l16] = h2u((half_t)neg);
            }
        }
        // ---- PV: wave-private LDS read (no barrier), plain f16 MFMA ----
#pragma unroll
        for (int kc = 0; kc < 2; ++kc) {
            const ushort* pr = &myP[l16][kc * 32 + lg * 8];
            const ushort* nr = &myN[l16][kc * 32 + lg * 8];
            UH8 tp, tn;
            *(int2*)&tp.i       = *(const int2*)pr;
            *(((int2*)&tp.i)+1) = *(const int2*)(pr + 4);
            *(int2*)&tn.i       = *(const int2*)nr;
            *(((int2*)&tn.i)+1) = *(const int2*)(nr + 4);
            const int ecol = j0 + kc * 32 + lg * 8;
#pragma unroll
            for (int cs = 0; cs < 4; ++cs) {
                const size_t eo = (size_t)(cs * 16 + l16) * N + ecol;
                half8 Ef = ldh(Et + eo);
                accP[cs] = MFMA16(tp.h, Ef, accP[cs]);
                accN[cs] = MFMA16(tn.h, Ef, accN[cs]);
            }
        }
    }
    // ---- deterministic 4-wave combine: ((w0+w2) + (w1+w3)) ----
    __syncthreads();
    float* scr = (float*)&PNs[0][0][0][0];
    if (w >= 2) {
        float* base = scr + (size_t)(w - 2) * 2048;
#pragma unroll
        for (int cs = 0; cs < 4; ++cs)
#pragma unroll
            for (int r = 0; r < 4; ++r) {
                const int idx = (lg * 4 + r) * 64 + cs * 16 + l16;
                base[idx]        = accP[cs][r];
                base[idx + 1024] = accN[cs][r];
            }
    }
    __syncthreads();
    if (w < 2) {
        const float* src = scr + (size_t)w * 2048;
#pragma unroll
        for (int cs = 0; cs < 4; ++cs)
#pragma unroll
            for (int r = 0; r < 4; ++r) {
                const int idx = (lg * 4 + r) * 64 + cs * 16 + l16;
                accP[cs][r] += src[idx];
                accN[cs][r] += src[idx + 1024];
            }
    }
    __syncthreads();
    if (w == 1) {
#pragma unroll
        for (int cs = 0; cs < 4; ++cs)
#pragma unroll
            for (int r = 0; r < 4; ++r) {
                const int idx = (lg * 4 + r) * 64 + cs * 16 + l16;
                scr[idx]        = accP[cs][r];
                scr[idx + 1024] = accN[cs][r];
            }
    }
    __syncthreads();
    if (w == 0) {
#pragma unroll
        for (int cs = 0; cs < 4; ++cs)
#pragma unroll
            for (int r = 0; r < 4; ++r) {
                const int idx = (lg * 4 + r) * 64 + cs * 16 + l16;
                const size_t off = ((size_t)js * N + i0 + lg * 4 + r) * 64 + cs * 16 + l16;
                Pp[off] = accP[cs][r] + scr[idx];
                Pn[off] = accN[cs][r] + scr[idx + 1024];
            }
    }
}

// Reduce 4 partials, row-softmax both, combine with fp32 E.
__global__ __launch_bounds__(256) void fin_msg(
    const float* __restrict__ Pp, const float* __restrict__ Pn,
    const float* __restrict__ E, float* __restrict__ outm)
{
    const int w = threadIdx.x >> 6, lane = threadIdx.x & 63;
    const int row = blockIdx.x * 4 + w;
    float lp = 0.f, ln = 0.f;
#pragma unroll
    for (int js = 0; js < 4; ++js) {
        lp += Pp[((size_t)js * N + row) * 64 + lane];
        ln += Pn[((size_t)js * N + row) * 64 + lane];
    }
    float mp = wave_max(lp);
    float ep = expf(lp - mp);
    float tp = wave_sum(ep); tp = __shfl(tp, 0, 64);
    float sp = ep / tp;
    float mn = wave_max(ln);
    float en = expf(ln - mn);
    float tn = wave_sum(en); tn = __shfl(tn, 0, 64);
    float sn = en / tn;
    outm[(size_t)row * 64 + lane] = (sp - sn + E[(size_t)row * 64 + lane]) * 0.5f;
}

__global__ void init_stats(float* stats)
{
    if (threadIdx.x < 128) stats[threadIdx.x] = 0.f;
}

extern "C" void kernel_launch(void* const* d_in, const int* in_sizes, int n_in,
                              void* d_out, int out_size, void* d_ws, size_t ws_size,
                              hipStream_t stream)
{
    const float* ori = (const float*)d_in[0];
    const float* smo = (const float*)d_in[1];
    // d_in[2] processed_feature: unused. d_in[3] universal_re: unused (beta=0).
    const float* Ws1 = (const float*)d_in[4];
    const float* bs1 = (const float*)d_in[5];
    const float* Ws2 = (const float*)d_in[6];
    const float* bs2 = (const float*)d_in[7];
    const float* Wl1 = (const float*)d_in[8];
    const float* bl1 = (const float*)d_in[9];
    const float* Wl2 = (const float*)d_in[10];
    const float* bl2 = (const float*)d_in[11];
    const float* Wh1 = (const float*)d_in[12];
    const float* bh1 = (const float*)d_in[13];
    const float* Wh2 = (const float*)d_in[14];
    const float* bh2 = (const float*)d_in[15];
    const float* am  = (const float*)d_in[16];
    const float* ah  = (const float*)d_in[17];

    float* out_ori = (float*)d_out;
    float* out_smo = out_ori + (size_t)N * 64;
    float* out_msg = out_smo + (size_t)N * 64;

    char* p = (char*)d_ws;
    float* h      = (float*)p;  p += (size_t)N * 256 * 4;    // 8 MB
    float* E      = (float*)p;  p += (size_t)N * 64 * 4;     // 2 MB
    float* Pp     = (float*)p;  p += (size_t)4 * N * 64 * 4; // 8 MB
    float* Pn     = (float*)p;  p += (size_t)4 * N * 64 * 4; // 8 MB
    ushort* uh    = (ushort*)p; p += (size_t)N * 64 * 2;     // 1 MB
    ushort* ul    = (ushort*)p; p += (size_t)N * 64 * 2;     // 1 MB
    ushort* Et    = (ushort*)p; p += (size_t)N * 64 * 2;     // 1 MB
    float* maxbuf = (float*)p;  p += 4096 * 4;               // 16 KB
    float* stats  = (float*)p;                               // 128 floats
    // total ~29.0 MB

    const dim3 b(256);
    init_stats<<<1, 128, 0, stream>>>(stats);

    // smooth path
    gemm_bias_act<<<dim3(128, 4), b, 0, stream>>>(smo, Ws1, bs1, am, h, 256, 512, 1);
    gemm_bias_act<<<dim3(128, 1), b, 0, stream>>>(h, Ws2, bs2, am, out_smo, 64, 256, 0);
    // local path
    gemm_bias_act<<<dim3(128, 4), b, 0, stream>>>(ori, Wl1, bl1, am, h, 256, 128, 1);
    gemm_bias_act<<<dim3(128, 1), b, 0, stream>>>(h, Wl2, bl2, am, out_ori, 64, 256, 0);
    // hete path -> feature_emb E
    gemm_bias_act<<<dim3(128, 4), b, 0, stream>>>(smo, Wh1, bh1, ah, h, 256, 512, 1);
    gemm_bias_act<<<dim3(128, 1), b, 0, stream>>>(h, Wh2, bh2, ah, E, 64, 256, 0);

    row_softmax_u<<<512, b, 0, stream>>>(E, uh, ul, stats);
    trans_e<<<128, b, 0, stream>>>(E, Et);
    pass_max_f16<<<dim3(512, 8), dim3(64), 0, stream>>>(uh, ul, maxbuf);
    fin_m<<<1, 256, 0, stream>>>(maxbuf, stats);
    pass_prop_f16<<<dim3(512, 4), b, 0, stream>>>(uh, ul, Et, stats, ah, Pp, Pn);
    fin_msg<<<2048, b, 0, stream>>>(Pp, Pn, E, out_msg);
}